// Round 1
// baseline (10329.889 us; speedup 1.0000x reference)
//
#include <hip/hip_runtime.h>
#include <hip/hip_bf16.h>
#include <cmath>

#define FD 32
#define SD 16
#define NSTEP 4096
#define VOCAB 50257
#define CD 48            // FD + SD
#define VC 64            // vocab chunks for logits pass
#define ROWS_PER ((VOCAB + VC - 1) / VC)   // 786

// ---------------- workspace layout (floats) ----------------
// xt      : [NSTEP][96]      @ 0          (gx[32], px[32], fx[32])
#define WS_XT     0
// states  : [NSTEP][48]      @ 393216
#define WS_STATES (NSTEP * 96)
// pm      : [NSTEP][VC][2]   @ 589824     (running max, running sumexp)
#define WS_PM     (WS_STATES + NSTEP * CD)
// tl      : [NSTEP]          @ 1114112    (target logit incl. bias)
#define WS_TL     (WS_PM + NSTEP * VC * 2)

// ---------------- K1: precompute token-dependent terms ----------------
__global__ __launch_bounds__(256) void xterm_kernel(
    const int* __restrict__ tok, const float* __restrict__ embed,
    const float* __restrict__ Wgx, const float* __restrict__ Wxp,
    const float* __restrict__ Wxf, float* __restrict__ xt)
{
    int t = blockIdx.x * 8 + (threadIdx.x >> 5);
    int i = threadIdx.x & 31;
    if (t >= NSTEP) return;
    const float* x = embed + (size_t)tok[t] * FD;
    float a0 = 0.f, a1 = 0.f, a2 = 0.f;
#pragma unroll
    for (int j = 0; j < FD; ++j) {
        float xj = x[j];
        a0 += Wgx[i * FD + j] * xj;
        a1 += Wxp[i * FD + j] * xj;
        a2 += Wxf[i * FD + j] * xj;
    }
    xt[t * 96 + i]      = a0;
    xt[t * 96 + 32 + i] = a1;
    xt[t * 96 + 64 + i] = a2;
}

// ---------------- K2: the serial scan (single wave) ----------------
__global__ __launch_bounds__(64) void scan_kernel(
    const float* __restrict__ Wgh, const float* __restrict__ bgh,
    const float* __restrict__ Wff, const float* __restrict__ bff,
    const float* __restrict__ Wfs,
    const float* __restrict__ Wsgf, const float* __restrict__ bsgf,
    const float* __restrict__ Wsgs, const float* __restrict__ Wss,
    const float* __restrict__ bss, const float* __restrict__ Wsf,
    const float* __restrict__ xt, float* __restrict__ states)
{
    // all weights stored TRANSPOSED in LDS: inner (last) index = output row,
    // so lanes read consecutive addresses -> conflict-free.
    __shared__ float sWghT[FD * FD];   // [j][i]
    __shared__ float sWffT[FD * FD];   // [j][i]
    __shared__ float sWfsT[SD * FD];   // [k][j]  (Wfs is (FD,SD): rows j<32, cols k<16)
    __shared__ float sWsgfT[FD * SD];  // [j][i]  (Wsgf is (SD,FD): rows i<16, cols j<32)
    __shared__ float sWsgsT[SD * SD];  // [k][i]
    __shared__ float sWssT[SD * SD];   // [k][i]
    __shared__ float sWsfT[FD * SD];   // [k][j]  (Wsf is (SD,FD): rows j<16, cols k<32)
    __shared__ float sbgh[FD], sbff[FD], sbsgf[SD], sbss[SD];
    __shared__ float hf[FD], hs[SD], hA[FD], hB[FD], c1[FD], stl[SD];

    const int tid = threadIdx.x;

    for (int idx = tid; idx < FD * FD; idx += 64) {
        int i = idx / FD, j = idx % FD;
        sWghT[j * FD + i] = Wgh[idx];
        sWffT[j * FD + i] = Wff[idx];
    }
    for (int idx = tid; idx < FD * SD; idx += 64) {   // Wfs (FD rows, SD cols)
        int j = idx / SD, k = idx % SD;
        sWfsT[k * FD + j] = Wfs[idx];
    }
    for (int idx = tid; idx < SD * FD; idx += 64) {   // Wsgf (SD rows, FD cols)
        int i = idx / FD, j = idx % FD;
        sWsgfT[j * SD + i] = Wsgf[idx];
    }
    for (int idx = tid; idx < SD * SD; idx += 64) {
        int i = idx / SD, k = idx % SD;
        sWsgsT[k * SD + i] = Wsgs[idx];
        sWssT[k * SD + i]  = Wss[idx];
    }
    for (int idx = tid; idx < SD * FD; idx += 64) {   // Wsf (SD rows, FD cols)
        int j = idx / FD, k = idx % FD;
        sWsfT[k * SD + j] = Wsf[idx];
    }
    if (tid < FD) { sbgh[tid] = bgh[tid]; sbff[tid] = bff[tid]; hf[tid] = 0.f; }
    if (tid < SD) { sbsgf[tid] = bsgf[tid]; sbss[tid] = bss[tid]; hs[tid] = 0.f; }
    __syncthreads();

    for (int t = 0; t < NSTEP; ++t) {
        const float* x = xt + t * 96;
        // Stage A: lanes 0-31 -> gate + h1 ; lanes 32-63 -> c1 = b_ff + fx + W_fs@h_slow
        if (tid < FD) {
            float acc = sbgh[tid] + x[tid];
#pragma unroll
            for (int j = 0; j < FD; ++j) acc += sWghT[j * FD + tid] * hf[j];
            float gate = 1.f / (1.f + __expf(-acc));
            hA[tid] = hf[tid] + gate * x[FD + tid];
        } else {
            int j = tid - FD;
            float acc = sbff[j] + x[64 + j];
#pragma unroll
            for (int k = 0; k < SD; ++k) acc += sWfsT[k * FD + j] * hs[k];
            c1[j] = acc;
        }
        __syncthreads();
        // Relax 1
        if (tid < FD) {
            float acc = c1[tid];
#pragma unroll
            for (int j = 0; j < FD; ++j) acc += sWffT[j * FD + tid] * hA[j];
            float tg = tanhf(acc);
            hB[tid] = hA[tid] + 0.25f * (tg - hA[tid]);
        }
        __syncthreads();
        // Relax 2
        if (tid < FD) {
            float acc = c1[tid];
#pragma unroll
            for (int j = 0; j < FD; ++j) acc += sWffT[j * FD + tid] * hB[j];
            float tg = tanhf(acc);
            float h3 = hB[tid] + 0.25f * (tg - hB[tid]);
            hf[tid] = h3;
            states[(size_t)t * CD + tid] = h3;
        }
        __syncthreads();
        // Slow stage: lanes 0-15 -> slow_gate ; lanes 16-31 -> slow_target
        float sg = 0.f;
        if (tid < SD) {
            float acc = sbsgf[tid];
#pragma unroll
            for (int j = 0; j < FD; ++j) acc += sWsgfT[j * SD + tid] * hf[j];
#pragma unroll
            for (int k = 0; k < SD; ++k) acc += sWsgsT[k * SD + tid] * hs[k];
            sg = 1.f / (1.f + __expf(-acc));
        } else if (tid < 2 * SD) {
            int j = tid - SD;
            float acc = sbss[j];
#pragma unroll
            for (int k = 0; k < SD; ++k) acc += sWssT[k * SD + j] * hs[k];
#pragma unroll
            for (int k = 0; k < FD; ++k) acc += sWsfT[k * SD + j] * hf[k];
            stl[j] = tanhf(acc);
        }
        __syncthreads();
        if (tid < SD) {
            float hsn = hs[tid] + 0.02f * sg * (stl[tid] - hs[tid]);
            hs[tid] = hsn;
            states[(size_t)t * CD + FD + tid] = hsn;
        }
        __syncthreads();
    }
}

// ---------------- K3: vocab logits + online logsumexp partials ----------------
// one thread = one timestep; wave-uniform row loop -> W_out rows via scalar loads
__global__ __launch_bounds__(256) void logits_kernel(
    const float* __restrict__ Wout, const float* __restrict__ bout,
    const float* __restrict__ states, float* __restrict__ pm)
{
    int t = blockIdx.y * 256 + threadIdx.x;      // 16 y-blocks x 256 = 4096
    int chunk = blockIdx.x;
    int r0 = chunk * ROWS_PER;
    int r1 = min(r0 + ROWS_PER, VOCAB);

    float s[CD];
#pragma unroll
    for (int k = 0; k < CD; ++k) s[k] = states[(size_t)t * CD + k];

    float m = -1e30f, sum = 0.f;
    for (int r = r0; r < r1; ++r) {
        const float* w = Wout + (size_t)r * CD;
        float acc = bout[r];
#pragma unroll
        for (int k = 0; k < CD; ++k) acc += w[k] * s[k];
        float nm = fmaxf(m, acc);
        sum = sum * __expf(m - nm) + __expf(acc - nm);
        m = nm;
    }
    pm[((size_t)t * VC + chunk) * 2]     = m;
    pm[((size_t)t * VC + chunk) * 2 + 1] = sum;
}

// ---------------- K4: target logits ----------------
__global__ __launch_bounds__(256) void tlogit_kernel(
    const int* __restrict__ tok, const float* __restrict__ Wout,
    const float* __restrict__ bout, const float* __restrict__ states,
    float* __restrict__ tl)
{
    int t = blockIdx.x * 256 + threadIdx.x;
    if (t >= NSTEP) return;
    int tgt = tok[t + 1];
    const float* w = Wout + (size_t)tgt * CD;
    float acc = bout[tgt];
#pragma unroll
    for (int k = 0; k < CD; ++k) acc += w[k] * states[(size_t)t * CD + k];
    tl[t] = acc;
}

// ---------------- K5: combine partials -> mean NLL ----------------
__global__ __launch_bounds__(256) void finalize_kernel(
    const float* __restrict__ pm, const float* __restrict__ tl,
    float* __restrict__ out)
{
    __shared__ float red[256];
    float local = 0.f;
    for (int t = threadIdx.x; t < NSTEP; t += 256) {
        float m = -1e30f;
        for (int c = 0; c < VC; ++c) m = fmaxf(m, pm[((size_t)t * VC + c) * 2]);
        float ssum = 0.f;
        for (int c = 0; c < VC; ++c)
            ssum += pm[((size_t)t * VC + c) * 2 + 1] *
                    __expf(pm[((size_t)t * VC + c) * 2] - m);
        float lse = m + __logf(ssum);
        local += lse - tl[t];
    }
    red[threadIdx.x] = local;
    __syncthreads();
    for (int off = 128; off > 0; off >>= 1) {
        if (threadIdx.x < off) red[threadIdx.x] += red[threadIdx.x + off];
        __syncthreads();
    }
    if (threadIdx.x == 0) out[0] = red[0] / (float)NSTEP;
}

extern "C" void kernel_launch(void* const* d_in, const int* in_sizes, int n_in,
                              void* d_out, int out_size, void* d_ws, size_t ws_size,
                              hipStream_t stream) {
    const int*   tok   = (const int*)  d_in[0];
    const float* embed = (const float*)d_in[1];
    const float* Wgh   = (const float*)d_in[2];
    const float* bgh   = (const float*)d_in[3];
    const float* Wgx   = (const float*)d_in[4];
    const float* Wxp   = (const float*)d_in[5];
    const float* Wff   = (const float*)d_in[6];
    const float* bff   = (const float*)d_in[7];
    const float* Wfs   = (const float*)d_in[8];
    const float* Wxf   = (const float*)d_in[9];
    const float* Wsgf  = (const float*)d_in[10];
    const float* bsgf  = (const float*)d_in[11];
    const float* Wsgs  = (const float*)d_in[12];
    const float* Wss   = (const float*)d_in[13];
    const float* bss   = (const float*)d_in[14];
    const float* Wsf   = (const float*)d_in[15];
    const float* Wout  = (const float*)d_in[16];
    const float* bout  = (const float*)d_in[17];

    float* ws     = (float*)d_ws;
    float* xt     = ws + WS_XT;
    float* states = ws + WS_STATES;
    float* pm     = ws + WS_PM;
    float* tl     = ws + WS_TL;
    float* outf   = (float*)d_out;

    xterm_kernel<<<dim3(NSTEP / 8), dim3(256), 0, stream>>>(tok, embed, Wgx, Wxp, Wxf, xt);
    scan_kernel<<<dim3(1), dim3(64), 0, stream>>>(Wgh, bgh, Wff, bff, Wfs, Wsgf, bsgf,
                                                  Wsgs, Wss, bss, Wsf, xt, states);
    logits_kernel<<<dim3(VC, NSTEP / 256), dim3(256), 0, stream>>>(Wout, bout, states, pm);
    tlogit_kernel<<<dim3(NSTEP / 256), dim3(256), 0, stream>>>(tok, Wout, bout, states, tl);
    finalize_kernel<<<dim3(1), dim3(256), 0, stream>>>(pm, tl, outf);
}

// Round 2
// 5407.270 us; speedup vs baseline: 1.9104x; 1.9104x over previous
//
#include <hip/hip_runtime.h>
#include <hip/hip_bf16.h>
#include <cmath>

#define FD 32
#define SD 16
#define NSTEP 4096
#define VOCAB 50257
#define CD 48            // FD + SD
#define VC 64            // vocab chunks for logits pass
#define ROWS_PER ((VOCAB + VC - 1) / VC)   // 786

// ---------------- workspace layout (floats) ----------------
#define WS_XT     0
#define WS_STATES (NSTEP * 96)
#define WS_PM     (WS_STATES + NSTEP * CD)
#define WS_TL     (WS_PM + NSTEP * VC * 2)

__device__ __forceinline__ float rl(float v, int l) {
    return __builtin_bit_cast(float, __builtin_amdgcn_readlane(__builtin_bit_cast(int, v), l));
}

// ---------------- K1: precompute token-dependent terms ----------------
__global__ __launch_bounds__(256) void xterm_kernel(
    const int* __restrict__ tok, const float* __restrict__ embed,
    const float* __restrict__ Wgx, const float* __restrict__ Wxp,
    const float* __restrict__ Wxf, float* __restrict__ xt)
{
    int t = blockIdx.x * 8 + (threadIdx.x >> 5);
    int i = threadIdx.x & 31;
    if (t >= NSTEP) return;
    const float* x = embed + (size_t)tok[t] * FD;
    float a0 = 0.f, a1 = 0.f, a2 = 0.f;
#pragma unroll
    for (int j = 0; j < FD; ++j) {
        float xj = x[j];
        a0 += Wgx[i * FD + j] * xj;
        a1 += Wxp[i * FD + j] * xj;
        a2 += Wxf[i * FD + j] * xj;
    }
    xt[t * 96 + i]      = a0;
    xt[t * 96 + 32 + i] = a1;
    xt[t * 96 + 64 + i] = a2;
}

// ---------------- K2: serial scan, all-register, readlane broadcast ----------------
// Lane layout:
//   lanes  0-31 (i): rows of W_gate_h (wA), W_ff (wB), W_fs (wC); state hf[i]
//   lanes 32-47 (s): rows of W_sg_f (wA), W_sg_s (wC); state hs[s]
//   lanes 48-63 (s): rows of W_sf   (wA), W_ss   (wC)
// Shared broadcast loops:
//   L1 over hs (16 iters): W_fs@hs (fast) + W_sg_s@hs + W_ss@hs (slow)
//   L2 over hf_new (32 iters): W_gate_h@hf (next step's gate) + W_sg_f@hf + W_sf@hf
// No LDS, no __syncthreads in the loop.
__global__ __launch_bounds__(64) void scan_kernel(
    const float* __restrict__ Wgh, const float* __restrict__ bgh,
    const float* __restrict__ Wff, const float* __restrict__ bff,
    const float* __restrict__ Wfs,
    const float* __restrict__ Wsgf, const float* __restrict__ bsgf,
    const float* __restrict__ Wsgs, const float* __restrict__ Wss,
    const float* __restrict__ bss, const float* __restrict__ Wsf,
    const float* __restrict__ xt, float* __restrict__ states)
{
    const int lane = threadIdx.x;
    float wA[FD], wB[FD], wC[SD];
    float bA = 0.f, bB = 0.f;

    if (lane < FD) {
#pragma unroll
        for (int j = 0; j < FD; ++j) { wA[j] = Wgh[lane * FD + j]; wB[j] = Wff[lane * FD + j]; }
#pragma unroll
        for (int k = 0; k < SD; ++k) wC[k] = Wfs[lane * SD + k];
        bA = bgh[lane]; bB = bff[lane];
    } else if (lane < FD + SD) {
        int s = lane - FD;
#pragma unroll
        for (int j = 0; j < FD; ++j) { wA[j] = Wsgf[s * FD + j]; wB[j] = 0.f; }
#pragma unroll
        for (int k = 0; k < SD; ++k) wC[k] = Wsgs[s * SD + k];
        bA = bsgf[s];
    } else {
        int s = lane - 48;
#pragma unroll
        for (int j = 0; j < FD; ++j) { wA[j] = Wsf[s * FD + j]; wB[j] = 0.f; }
#pragma unroll
        for (int k = 0; k < SD; ++k) wC[k] = Wss[s * SD + k];
        bA = bss[s];
    }

    float hf = 0.f;   // valid lanes 0-31
    float hs = 0.f;   // valid lanes 32-47
    float pA = 0.f;   // fast: W_gate_h@hf carry; slow: W_sg_f@hf / W_sf@hf (same-step)

    float gx = 0.f, px = 0.f, fx = 0.f;
    if (lane < FD) { gx = xt[lane]; px = xt[FD + lane]; fx = xt[64 + lane]; }

    for (int t = 0; t < NSTEP; ++t) {
        // prefetch next step's token terms (latency hidden behind compute)
        int tn = (t + 1 < NSTEP) ? t + 1 : t;
        float ngx = 0.f, npx = 0.f, nfx = 0.f;
        if (lane < FD) {
            ngx = xt[tn * 96 + lane];
            npx = xt[tn * 96 + 32 + lane];
            nfx = xt[tn * 96 + 64 + lane];
        }

        // L1: pC = sum_k wC[k] * hs[k]   (hs lives in lanes 32..47)
        float c0 = 0.f, c1p = 0.f, c2 = 0.f, c3 = 0.f;
#pragma unroll
        for (int k = 0; k < SD; k += 4) {
            c0  += wC[k]     * rl(hs, FD + k);
            c1p += wC[k + 1] * rl(hs, FD + k + 1);
            c2  += wC[k + 2] * rl(hs, FD + k + 2);
            c3  += wC[k + 3] * rl(hs, FD + k + 3);
        }
        float pC = (c0 + c1p) + (c2 + c3);

        // gate (fast lanes): pA = W_gate_h @ hf carried from previous L2
        float ga   = pA + bA + gx;
        float ge   = __expf(-ga);
        float gate = __builtin_amdgcn_rcpf(1.f + ge);
        float hA   = hf + gate * px;

        float c1 = bB + fx + pC;   // fast lanes: b_ff + x_drive + W_fs@hs

        // relax 1
        float hB;
        {
            float a0 = 0.f, a1 = 0.f, a2 = 0.f, a3 = 0.f;
#pragma unroll
            for (int j = 0; j < FD; j += 4) {
                a0 += wB[j]     * rl(hA, j);
                a1 += wB[j + 1] * rl(hA, j + 1);
                a2 += wB[j + 2] * rl(hA, j + 2);
                a3 += wB[j + 3] * rl(hA, j + 3);
            }
            float acc = c1 + ((a0 + a1) + (a2 + a3));
            float e  = __expf(-2.f * acc);
            float tg = 2.f * __builtin_amdgcn_rcpf(1.f + e) - 1.f;
            hB = hA + 0.25f * (tg - hA);
        }
        // relax 2
        {
            float a0 = 0.f, a1 = 0.f, a2 = 0.f, a3 = 0.f;
#pragma unroll
            for (int j = 0; j < FD; j += 4) {
                a0 += wB[j]     * rl(hB, j);
                a1 += wB[j + 1] * rl(hB, j + 1);
                a2 += wB[j + 2] * rl(hB, j + 2);
                a3 += wB[j + 3] * rl(hB, j + 3);
            }
            float acc = c1 + ((a0 + a1) + (a2 + a3));
            float e  = __expf(-2.f * acc);
            float tg = 2.f * __builtin_amdgcn_rcpf(1.f + e) - 1.f;
            hf = hB + 0.25f * (tg - hB);
        }

        // L2: pA = sum_j wA[j] * hf_new[j]
        //   fast lanes -> gate matvec for step t+1; slow lanes -> W_sg_f@hf / W_sf@hf for this step
        {
            float a0 = 0.f, a1 = 0.f, a2 = 0.f, a3 = 0.f;
#pragma unroll
            for (int j = 0; j < FD; j += 4) {
                a0 += wA[j]     * rl(hf, j);
                a1 += wA[j + 1] * rl(hf, j + 1);
                a2 += wA[j + 2] * rl(hf, j + 2);
                a3 += wA[j + 3] * rl(hf, j + 3);
            }
            pA = (a0 + a1) + (a2 + a3);
        }

        // slow update: lanes 32-47 sigmoid (sg), lanes 48-63 tanh (st)
        {
            float u = bA + pC + pA;
            bool isST = (lane >= 48);
            float e = __expf(isST ? (-2.f * u) : (-u));
            float r = __builtin_amdgcn_rcpf(1.f + e);
            float v = isST ? (2.f * r - 1.f) : r;        // st = (1-e)/(1+e) ; sg = 1/(1+e)
            float stv = __shfl(v, lane + 16, 64);        // lanes 32-47 <- st from lane+16
            float hsn = hs + 0.02f * v * (stv - hs);
            if (lane >= FD && lane < FD + SD) hs = hsn;
        }

        // store concat state
        if (lane < CD) states[(size_t)t * CD + lane] = (lane < FD) ? hf : hs;

        gx = ngx; px = npx; fx = nfx;
    }
}

// ---------------- K3: vocab logits + online logsumexp partials ----------------
__global__ __launch_bounds__(256) void logits_kernel(
    const float* __restrict__ Wout, const float* __restrict__ bout,
    const float* __restrict__ states, float* __restrict__ pm)
{
    int t = blockIdx.y * 256 + threadIdx.x;
    int chunk = blockIdx.x;
    int r0 = chunk * ROWS_PER;
    int r1 = min(r0 + ROWS_PER, VOCAB);

    float s[CD];
#pragma unroll
    for (int k = 0; k < CD; ++k) s[k] = states[(size_t)t * CD + k];

    float m = -1e30f, sum = 0.f;
    for (int r = r0; r < r1; ++r) {
        const float* w = Wout + (size_t)r * CD;
        float acc = bout[r];
#pragma unroll
        for (int k = 0; k < CD; ++k) acc += w[k] * s[k];
        float nm = fmaxf(m, acc);
        sum = sum * __expf(m - nm) + __expf(acc - nm);
        m = nm;
    }
    pm[((size_t)t * VC + chunk) * 2]     = m;
    pm[((size_t)t * VC + chunk) * 2 + 1] = sum;
}

// ---------------- K4: target logits ----------------
__global__ __launch_bounds__(256) void tlogit_kernel(
    const int* __restrict__ tok, const float* __restrict__ Wout,
    const float* __restrict__ bout, const float* __restrict__ states,
    float* __restrict__ tl)
{
    int t = blockIdx.x * 256 + threadIdx.x;
    if (t >= NSTEP) return;
    int tgt = tok[t + 1];
    const float* w = Wout + (size_t)tgt * CD;
    float acc = bout[tgt];
#pragma unroll
    for (int k = 0; k < CD; ++k) acc += w[k] * states[(size_t)t * CD + k];
    tl[t] = acc;
}

// ---------------- K5: combine partials -> mean NLL ----------------
__global__ __launch_bounds__(256) void finalize_kernel(
    const float* __restrict__ pm, const float* __restrict__ tl,
    float* __restrict__ out)
{
    __shared__ float red[256];
    float local = 0.f;
    for (int t = threadIdx.x; t < NSTEP; t += 256) {
        float m = -1e30f;
        for (int c = 0; c < VC; ++c) m = fmaxf(m, pm[((size_t)t * VC + c) * 2]);
        float ssum = 0.f;
        for (int c = 0; c < VC; ++c)
            ssum += pm[((size_t)t * VC + c) * 2 + 1] *
                    __expf(pm[((size_t)t * VC + c) * 2] - m);
        float lse = m + __logf(ssum);
        local += lse - tl[t];
    }
    red[threadIdx.x] = local;
    __syncthreads();
    for (int off = 128; off > 0; off >>= 1) {
        if (threadIdx.x < off) red[threadIdx.x] += red[threadIdx.x + off];
        __syncthreads();
    }
    if (threadIdx.x == 0) out[0] = red[0] / (float)NSTEP;
}

extern "C" void kernel_launch(void* const* d_in, const int* in_sizes, int n_in,
                              void* d_out, int out_size, void* d_ws, size_t ws_size,
                              hipStream_t stream) {
    const int*   tok   = (const int*)  d_in[0];
    const float* embed = (const float*)d_in[1];
    const float* Wgh   = (const float*)d_in[2];
    const float* bgh   = (const float*)d_in[3];
    const float* Wgx   = (const float*)d_in[4];
    const float* Wxp   = (const float*)d_in[5];
    const float* Wff   = (const float*)d_in[6];
    const float* bff   = (const float*)d_in[7];
    const float* Wfs   = (const float*)d_in[8];
    const float* Wxf   = (const float*)d_in[9];
    const float* Wsgf  = (const float*)d_in[10];
    const float* bsgf  = (const float*)d_in[11];
    const float* Wsgs  = (const float*)d_in[12];
    const float* Wss   = (const float*)d_in[13];
    const float* bss   = (const float*)d_in[14];
    const float* Wsf   = (const float*)d_in[15];
    const float* Wout  = (const float*)d_in[16];
    const float* bout  = (const float*)d_in[17];

    float* ws     = (float*)d_ws;
    float* xt     = ws + WS_XT;
    float* states = ws + WS_STATES;
    float* pm     = ws + WS_PM;
    float* tl     = ws + WS_TL;
    float* outf   = (float*)d_out;

    xterm_kernel<<<dim3(NSTEP / 8), dim3(256), 0, stream>>>(tok, embed, Wgx, Wxp, Wxf, xt);
    scan_kernel<<<dim3(1), dim3(64), 0, stream>>>(Wgh, bgh, Wff, bff, Wfs, Wsgf, bsgf,
                                                  Wsgs, Wss, bss, Wsf, xt, states);
    logits_kernel<<<dim3(VC, NSTEP / 256), dim3(256), 0, stream>>>(Wout, bout, states, pm);
    tlogit_kernel<<<dim3(NSTEP / 256), dim3(256), 0, stream>>>(tok, Wout, bout, states, tl);
    finalize_kernel<<<dim3(1), dim3(256), 0, stream>>>(pm, tl, outf);
}

// Round 3
// 3273.519 us; speedup vs baseline: 3.1556x; 1.6518x over previous
//
#include <hip/hip_runtime.h>
#include <hip/hip_bf16.h>
#include <cmath>

#define FD 32
#define SD 16
#define NSTEP 4096
#define VOCAB 50257
#define CD 48            // FD + SD
#define VC 64            // vocab chunks for logits pass
#define ROWS_PER ((VOCAB + VC - 1) / VC)   // 786

// ---------------- workspace layout (floats) ----------------
#define WS_XT     0
#define WS_STATES (NSTEP * 96)
#define WS_PM     (WS_STATES + NSTEP * CD)
#define WS_TL     (WS_PM + NSTEP * VC * 2)

__device__ __forceinline__ float rl(float v, int l) {
    return __builtin_bit_cast(float, __builtin_amdgcn_readlane(__builtin_bit_cast(int, v), l));
}

// ---------------- K1: precompute token-dependent terms ----------------
__global__ __launch_bounds__(256) void xterm_kernel(
    const int* __restrict__ tok, const float* __restrict__ embed,
    const float* __restrict__ Wgx, const float* __restrict__ Wxp,
    const float* __restrict__ Wxf, float* __restrict__ xt)
{
    int t = blockIdx.x * 8 + (threadIdx.x >> 5);
    int i = threadIdx.x & 31;
    if (t >= NSTEP) return;
    const float* x = embed + (size_t)tok[t] * FD;
    float a0 = 0.f, a1 = 0.f, a2 = 0.f;
#pragma unroll
    for (int j = 0; j < FD; ++j) {
        float xj = x[j];
        a0 += Wgx[i * FD + j] * xj;
        a1 += Wxp[i * FD + j] * xj;
        a2 += Wxf[i * FD + j] * xj;
    }
    xt[t * 96 + i]      = a0;
    xt[t * 96 + 32 + i] = a1;
    xt[t * 96 + 64 + i] = a2;
}

// ---------------- K2: serial scan, all-register, batched-readlane broadcast ----------------
// Lane layout:
//   lanes  0-31 (i): rows of W_gate_h (wA), W_ff (wB), W_fs (wC); state hf[i]
//   lanes 32-47 (s): rows of W_sg_f (wA), W_sg_s (wC); state hs[s]
//   lanes 48-63 (s): rows of W_sf   (wA), W_ss   (wC)
// Matvec pattern: gather ALL broadcasts into SGPRs first (independent ops),
// then one FMA stream with 8-way accumulator split. No LDS, no barriers.
__global__ __launch_bounds__(64) void scan_kernel(
    const float* __restrict__ Wgh, const float* __restrict__ bgh,
    const float* __restrict__ Wff, const float* __restrict__ bff,
    const float* __restrict__ Wfs,
    const float* __restrict__ Wsgf, const float* __restrict__ bsgf,
    const float* __restrict__ Wsgs, const float* __restrict__ Wss,
    const float* __restrict__ bss, const float* __restrict__ Wsf,
    const float* __restrict__ xt, float* __restrict__ states)
{
    const int lane = threadIdx.x;
    float wA[FD], wB[FD], wC[SD];
    float bA = 0.f, bB = 0.f;

    if (lane < FD) {
#pragma unroll
        for (int j = 0; j < FD; ++j) { wA[j] = Wgh[lane * FD + j]; wB[j] = Wff[lane * FD + j]; }
#pragma unroll
        for (int k = 0; k < SD; ++k) wC[k] = Wfs[lane * SD + k];
        bA = bgh[lane]; bB = bff[lane];
    } else if (lane < FD + SD) {
        int s = lane - FD;
#pragma unroll
        for (int j = 0; j < FD; ++j) { wA[j] = Wsgf[s * FD + j]; wB[j] = 0.f; }
#pragma unroll
        for (int k = 0; k < SD; ++k) wC[k] = Wsgs[s * SD + k];
        bA = bsgf[s];
    } else {
        int s = lane - 48;
#pragma unroll
        for (int j = 0; j < FD; ++j) { wA[j] = Wsf[s * FD + j]; wB[j] = 0.f; }
#pragma unroll
        for (int k = 0; k < SD; ++k) wC[k] = Wss[s * SD + k];
        bA = bss[s];
    }

    float hf = 0.f;   // valid lanes 0-31
    float hs = 0.f;   // valid lanes 32-47
    float pA = 0.f;   // fast: W_gate_h@hf carry; slow: W_sg_f@hf / W_sf@hf

    const int li = lane & 31;                 // branchless xt lane index
    const float* xp = xt + li;                // current row pointer (+li)
    float gx = xp[0], px = xp[FD], fx = xp[64];
    float* sp = states + lane;                // store pointer

    for (int t = 0; t < NSTEP; ++t) {
        // prefetch next step's token terms (branchless; upper lanes duplicate)
        const float* xpn = (t + 1 < NSTEP) ? xp + 96 : xp;
        float ngx = xpn[0], npx = xpn[FD], nfx = xpn[64];

        // ---- L1: pC = sum_k wC[k] * hs[k]  (hs in lanes 32..47) ----
        float pC;
        {
            float sv[SD];
#pragma unroll
            for (int k = 0; k < SD; ++k) sv[k] = rl(hs, FD + k);
            float a0 = 0.f, a1 = 0.f, a2 = 0.f, a3 = 0.f;
#pragma unroll
            for (int k = 0; k < SD; k += 4) {
                a0 += wC[k]     * sv[k];
                a1 += wC[k + 1] * sv[k + 1];
                a2 += wC[k + 2] * sv[k + 2];
                a3 += wC[k + 3] * sv[k + 3];
            }
            pC = (a0 + a1) + (a2 + a3);
        }

        // gate (fast lanes): pA = W_gate_h @ hf carried from previous L2
        float ga   = pA + bA + gx;
        float ge   = __expf(-ga);
        float gate = __builtin_amdgcn_rcpf(1.f + ge);
        float hA   = hf + gate * px;

        float c1 = bB + fx + pC;   // fast lanes: b_ff + x_drive + W_fs@hs

        // ---- relax 1 ----
        float hB;
        {
            float sv[FD];
#pragma unroll
            for (int j = 0; j < FD; ++j) sv[j] = rl(hA, j);
            float a0 = 0.f, a1 = 0.f, a2 = 0.f, a3 = 0.f;
            float a4 = 0.f, a5 = 0.f, a6 = 0.f, a7 = 0.f;
#pragma unroll
            for (int j = 0; j < FD; j += 8) {
                a0 += wB[j]     * sv[j];
                a1 += wB[j + 1] * sv[j + 1];
                a2 += wB[j + 2] * sv[j + 2];
                a3 += wB[j + 3] * sv[j + 3];
                a4 += wB[j + 4] * sv[j + 4];
                a5 += wB[j + 5] * sv[j + 5];
                a6 += wB[j + 6] * sv[j + 6];
                a7 += wB[j + 7] * sv[j + 7];
            }
            float acc = c1 + (((a0 + a1) + (a2 + a3)) + ((a4 + a5) + (a6 + a7)));
            float e  = __expf(-2.f * acc);
            float tg = 2.f * __builtin_amdgcn_rcpf(1.f + e) - 1.f;
            hB = hA + 0.25f * (tg - hA);
        }
        // ---- relax 2 ----
        {
            float sv[FD];
#pragma unroll
            for (int j = 0; j < FD; ++j) sv[j] = rl(hB, j);
            float a0 = 0.f, a1 = 0.f, a2 = 0.f, a3 = 0.f;
            float a4 = 0.f, a5 = 0.f, a6 = 0.f, a7 = 0.f;
#pragma unroll
            for (int j = 0; j < FD; j += 8) {
                a0 += wB[j]     * sv[j];
                a1 += wB[j + 1] * sv[j + 1];
                a2 += wB[j + 2] * sv[j + 2];
                a3 += wB[j + 3] * sv[j + 3];
                a4 += wB[j + 4] * sv[j + 4];
                a5 += wB[j + 5] * sv[j + 5];
                a6 += wB[j + 6] * sv[j + 6];
                a7 += wB[j + 7] * sv[j + 7];
            }
            float acc = c1 + (((a0 + a1) + (a2 + a3)) + ((a4 + a5) + (a6 + a7)));
            float e  = __expf(-2.f * acc);
            float tg = 2.f * __builtin_amdgcn_rcpf(1.f + e) - 1.f;
            hf = hB + 0.25f * (tg - hB);
        }

        // ---- L2: pA = sum_j wA[j] * hf_new[j] ----
        {
            float sv[FD];
#pragma unroll
            for (int j = 0; j < FD; ++j) sv[j] = rl(hf, j);
            float a0 = 0.f, a1 = 0.f, a2 = 0.f, a3 = 0.f;
            float a4 = 0.f, a5 = 0.f, a6 = 0.f, a7 = 0.f;
#pragma unroll
            for (int j = 0; j < FD; j += 8) {
                a0 += wA[j]     * sv[j];
                a1 += wA[j + 1] * sv[j + 1];
                a2 += wA[j + 2] * sv[j + 2];
                a3 += wA[j + 3] * sv[j + 3];
                a4 += wA[j + 4] * sv[j + 4];
                a5 += wA[j + 5] * sv[j + 5];
                a6 += wA[j + 6] * sv[j + 6];
                a7 += wA[j + 7] * sv[j + 7];
            }
            pA = (((a0 + a1) + (a2 + a3)) + ((a4 + a5) + (a6 + a7)));
        }

        // ---- slow update: lanes 32-47 sigmoid (sg), lanes 48-63 tanh (st) ----
        {
            float u = bA + pC + pA;
            bool isST = (lane >= 48);
            float e = __expf(isST ? (-2.f * u) : (-u));
            float r = __builtin_amdgcn_rcpf(1.f + e);
            float v = isST ? (2.f * r - 1.f) : r;        // st = (1-e)/(1+e) ; sg = 1/(1+e)
            float stv = __shfl(v, lane + 16, 64);        // lanes 32-47 <- st from lane+16
            float hsn = hs + 0.02f * v * (stv - hs);
            if (lane >= FD && lane < FD + SD) hs = hsn;
        }

        // store concat state
        if (lane < CD) sp[0] = (lane < FD) ? hf : hs;
        sp += CD;
        xp += 96;

        gx = ngx; px = npx; fx = nfx;
    }
}

// ---------------- K3: vocab logits + online logsumexp partials ----------------
__global__ __launch_bounds__(256) void logits_kernel(
    const float* __restrict__ Wout, const float* __restrict__ bout,
    const float* __restrict__ states, float* __restrict__ pm)
{
    int t = blockIdx.y * 256 + threadIdx.x;
    int chunk = blockIdx.x;
    int r0 = chunk * ROWS_PER;
    int r1 = min(r0 + ROWS_PER, VOCAB);

    float s[CD];
#pragma unroll
    for (int k = 0; k < CD; ++k) s[k] = states[(size_t)t * CD + k];

    float m = -1e30f, sum = 0.f;
    for (int r = r0; r < r1; ++r) {
        const float* w = Wout + (size_t)r * CD;
        float acc = bout[r];
#pragma unroll
        for (int k = 0; k < CD; ++k) acc += w[k] * s[k];
        float nm = fmaxf(m, acc);
        sum = sum * __expf(m - nm) + __expf(acc - nm);
        m = nm;
    }
    pm[((size_t)t * VC + chunk) * 2]     = m;
    pm[((size_t)t * VC + chunk) * 2 + 1] = sum;
}

// ---------------- K4: target logits ----------------
__global__ __launch_bounds__(256) void tlogit_kernel(
    const int* __restrict__ tok, const float* __restrict__ Wout,
    const float* __restrict__ bout, const float* __restrict__ states,
    float* __restrict__ tl)
{
    int t = blockIdx.x * 256 + threadIdx.x;
    if (t >= NSTEP) return;
    int tgt = tok[t + 1];
    const float* w = Wout + (size_t)tgt * CD;
    float acc = bout[tgt];
#pragma unroll
    for (int k = 0; k < CD; ++k) acc += w[k] * states[(size_t)t * CD + k];
    tl[t] = acc;
}

// ---------------- K5: combine partials -> mean NLL ----------------
__global__ __launch_bounds__(256) void finalize_kernel(
    const float* __restrict__ pm, const float* __restrict__ tl,
    float* __restrict__ out)
{
    __shared__ float red[256];
    float local = 0.f;
    for (int t = threadIdx.x; t < NSTEP; t += 256) {
        float m = -1e30f;
        for (int c = 0; c < VC; ++c) m = fmaxf(m, pm[((size_t)t * VC + c) * 2]);
        float ssum = 0.f;
        for (int c = 0; c < VC; ++c)
            ssum += pm[((size_t)t * VC + c) * 2 + 1] *
                    __expf(pm[((size_t)t * VC + c) * 2] - m);
        float lse = m + __logf(ssum);
        local += lse - tl[t];
    }
    red[threadIdx.x] = local;
    __syncthreads();
    for (int off = 128; off > 0; off >>= 1) {
        if (threadIdx.x < off) red[threadIdx.x] += red[threadIdx.x + off];
        __syncthreads();
    }
    if (threadIdx.x == 0) out[0] = red[0] / (float)NSTEP;
}

extern "C" void kernel_launch(void* const* d_in, const int* in_sizes, int n_in,
                              void* d_out, int out_size, void* d_ws, size_t ws_size,
                              hipStream_t stream) {
    const int*   tok   = (const int*)  d_in[0];
    const float* embed = (const float*)d_in[1];
    const float* Wgh   = (const float*)d_in[2];
    const float* bgh   = (const float*)d_in[3];
    const float* Wgx   = (const float*)d_in[4];
    const float* Wxp   = (const float*)d_in[5];
    const float* Wff   = (const float*)d_in[6];
    const float* bff   = (const float*)d_in[7];
    const float* Wfs   = (const float*)d_in[8];
    const float* Wxf   = (const float*)d_in[9];
    const float* Wsgf  = (const float*)d_in[10];
    const float* bsgf  = (const float*)d_in[11];
    const float* Wsgs  = (const float*)d_in[12];
    const float* Wss   = (const float*)d_in[13];
    const float* bss   = (const float*)d_in[14];
    const float* Wsf   = (const float*)d_in[15];
    const float* Wout  = (const float*)d_in[16];
    const float* bout  = (const float*)d_in[17];

    float* ws     = (float*)d_ws;
    float* xt     = ws + WS_XT;
    float* states = ws + WS_STATES;
    float* pm     = ws + WS_PM;
    float* tl     = ws + WS_TL;
    float* outf   = (float*)d_out;

    xterm_kernel<<<dim3(NSTEP / 8), dim3(256), 0, stream>>>(tok, embed, Wgx, Wxp, Wxf, xt);
    scan_kernel<<<dim3(1), dim3(64), 0, stream>>>(Wgh, bgh, Wff, bff, Wfs, Wsgf, bsgf,
                                                  Wsgs, Wss, bss, Wsf, xt, states);
    logits_kernel<<<dim3(VC, NSTEP / 256), dim3(256), 0, stream>>>(Wout, bout, states, pm);
    tlogit_kernel<<<dim3(NSTEP / 256), dim3(256), 0, stream>>>(tok, Wout, bout, states, tl);
    finalize_kernel<<<dim3(1), dim3(256), 0, stream>>>(pm, tl, outf);
}

// Round 4
// 3204.667 us; speedup vs baseline: 3.2234x; 1.0215x over previous
//
#include <hip/hip_runtime.h>
#include <hip/hip_bf16.h>
#include <cmath>

#define FD 32
#define SD 16
#define NSTEP 4096
#define VOCAB 50257
#define CD 48            // FD + SD
#define VC 64            // vocab chunks for logits pass
#define ROWS_PER ((VOCAB + VC - 1) / VC)   // 786
#define PIPE 4           // xt prefetch depth in the scan

// ---------------- workspace layout (floats) ----------------
#define WS_XT     0
#define WS_STATES ((NSTEP + PIPE) * 96)          // xt has PIPE rows of slack
#define WS_PM     (WS_STATES + NSTEP * CD)
#define WS_TL     (WS_PM + NSTEP * VC)
#define WS_NLL    (WS_TL + NSTEP)

__device__ __forceinline__ float rl(float v, int l) {
    return __builtin_bit_cast(float, __builtin_amdgcn_readlane(__builtin_bit_cast(int, v), l));
}

// ---------------- K1: precompute token-dependent terms ----------------
__global__ __launch_bounds__(256) void xterm_kernel(
    const int* __restrict__ tok, const float* __restrict__ embed,
    const float* __restrict__ Wgx, const float* __restrict__ Wxp,
    const float* __restrict__ Wxf, float* __restrict__ xt)
{
    int t = blockIdx.x * 8 + (threadIdx.x >> 5);
    int i = threadIdx.x & 31;
    if (t >= NSTEP) return;
    const float* x = embed + (size_t)tok[t] * FD;
    float a0 = 0.f, a1 = 0.f, a2 = 0.f;
#pragma unroll
    for (int j = 0; j < FD; ++j) {
        float xj = x[j];
        a0 += Wgx[i * FD + j] * xj;
        a1 += Wxp[i * FD + j] * xj;
        a2 += Wxf[i * FD + j] * xj;
    }
    xt[t * 96 + i]      = a0;
    xt[t * 96 + 32 + i] = a1;
    xt[t * 96 + 64 + i] = a2;
}

// ---------------- K2: serial scan, all-register, depth-4 load pipeline ----------------
// Lane layout:
//   lanes  0-31 (i): rows of W_gate_h (wA), W_ff (wB), W_fs (wC); state hf[i]
//   lanes 32-47 (s): rows of W_sg_f (wA), W_sg_s (wC); state hs[s]
//   lanes 48-63 (s): rows of W_sf   (wA), W_ss   (wC)
// Matvecs: batch ALL readlane broadcasts into SGPRs, then 8-way-split FMA stream.
// xt rows prefetched PIPE=4 steps ahead (distance ~4 bodies > HBM latency).
__global__ __launch_bounds__(64) void scan_kernel(
    const float* __restrict__ Wgh, const float* __restrict__ bgh,
    const float* __restrict__ Wff, const float* __restrict__ bff,
    const float* __restrict__ Wfs,
    const float* __restrict__ Wsgf, const float* __restrict__ bsgf,
    const float* __restrict__ Wsgs, const float* __restrict__ Wss,
    const float* __restrict__ bss, const float* __restrict__ Wsf,
    const float* __restrict__ xt, float* __restrict__ states)
{
    const int lane = threadIdx.x;
    float wA[FD], wB[FD], wC[SD];
    float bA = 0.f, bB = 0.f;

    if (lane < FD) {
#pragma unroll
        for (int j = 0; j < FD; ++j) { wA[j] = Wgh[lane * FD + j]; wB[j] = Wff[lane * FD + j]; }
#pragma unroll
        for (int k = 0; k < SD; ++k) wC[k] = Wfs[lane * SD + k];
        bA = bgh[lane]; bB = bff[lane];
    } else if (lane < FD + SD) {
        int s = lane - FD;
#pragma unroll
        for (int j = 0; j < FD; ++j) { wA[j] = Wsgf[s * FD + j]; wB[j] = 0.f; }
#pragma unroll
        for (int k = 0; k < SD; ++k) wC[k] = Wsgs[s * SD + k];
        bA = bsgf[s];
    } else {
        int s = lane - 48;
#pragma unroll
        for (int j = 0; j < FD; ++j) { wA[j] = Wsf[s * FD + j]; wB[j] = 0.f; }
#pragma unroll
        for (int k = 0; k < SD; ++k) wC[k] = Wss[s * SD + k];
        bA = bss[s];
    }

    float hf = 0.f;   // valid lanes 0-31
    float hs = 0.f;   // valid lanes 32-47
    float pA = 0.f;   // fast: W_gate_h@hf carry; slow: W_sg_f@hf / W_sf@hf

    const int li = lane & 31;
    const float* xp = xt + li;
    // fill the pipeline: rows 0..PIPE-1
    float pgx[PIPE], ppx[PIPE], pfx[PIPE];
#pragma unroll
    for (int d = 0; d < PIPE; ++d) {
        pgx[d] = xp[d * 96];
        ppx[d] = xp[d * 96 + FD];
        pfx[d] = xp[d * 96 + 64];
    }
    const float* xload = xp + PIPE * 96;   // next row to fetch (slack rows cover the tail)
    float* sp = states + lane;

    for (int t4 = 0; t4 < NSTEP; t4 += PIPE) {
#pragma unroll
        for (int d = 0; d < PIPE; ++d) {
            float gx = pgx[d], px = ppx[d], fx = pfx[d];
            // prefetch row t4+PIPE+d (consumed PIPE steps later)
            pgx[d] = xload[0]; ppx[d] = xload[FD]; pfx[d] = xload[64];
            xload += 96;

            // ---- L1: pC = sum_k wC[k] * hs[k]  (hs in lanes 32..47) ----
            float pC;
            {
                float sv[SD];
#pragma unroll
                for (int k = 0; k < SD; ++k) sv[k] = rl(hs, FD + k);
                float a0 = 0.f, a1 = 0.f, a2 = 0.f, a3 = 0.f;
#pragma unroll
                for (int k = 0; k < SD; k += 4) {
                    a0 += wC[k]     * sv[k];
                    a1 += wC[k + 1] * sv[k + 1];
                    a2 += wC[k + 2] * sv[k + 2];
                    a3 += wC[k + 3] * sv[k + 3];
                }
                pC = (a0 + a1) + (a2 + a3);
            }

            // gate (fast lanes): pA = W_gate_h @ hf carried from previous L2
            float ga   = pA + bA + gx;
            float ge   = __expf(-ga);
            float gate = __builtin_amdgcn_rcpf(1.f + ge);
            float hA   = hf + gate * px;

            float c1 = bB + fx + pC;   // fast lanes: b_ff + x_drive + W_fs@hs

            // ---- relax 1 ----
            float hB;
            {
                float sv[FD];
#pragma unroll
                for (int j = 0; j < FD; ++j) sv[j] = rl(hA, j);
                float a0 = 0.f, a1 = 0.f, a2 = 0.f, a3 = 0.f;
                float a4 = 0.f, a5 = 0.f, a6 = 0.f, a7 = 0.f;
#pragma unroll
                for (int j = 0; j < FD; j += 8) {
                    a0 += wB[j]     * sv[j];
                    a1 += wB[j + 1] * sv[j + 1];
                    a2 += wB[j + 2] * sv[j + 2];
                    a3 += wB[j + 3] * sv[j + 3];
                    a4 += wB[j + 4] * sv[j + 4];
                    a5 += wB[j + 5] * sv[j + 5];
                    a6 += wB[j + 6] * sv[j + 6];
                    a7 += wB[j + 7] * sv[j + 7];
                }
                float acc = c1 + (((a0 + a1) + (a2 + a3)) + ((a4 + a5) + (a6 + a7)));
                float e  = __expf(-2.f * acc);
                float tg = 2.f * __builtin_amdgcn_rcpf(1.f + e) - 1.f;
                hB = hA + 0.25f * (tg - hA);
            }
            // ---- relax 2 ----
            {
                float sv[FD];
#pragma unroll
                for (int j = 0; j < FD; ++j) sv[j] = rl(hB, j);
                float a0 = 0.f, a1 = 0.f, a2 = 0.f, a3 = 0.f;
                float a4 = 0.f, a5 = 0.f, a6 = 0.f, a7 = 0.f;
#pragma unroll
                for (int j = 0; j < FD; j += 8) {
                    a0 += wB[j]     * sv[j];
                    a1 += wB[j + 1] * sv[j + 1];
                    a2 += wB[j + 2] * sv[j + 2];
                    a3 += wB[j + 3] * sv[j + 3];
                    a4 += wB[j + 4] * sv[j + 4];
                    a5 += wB[j + 5] * sv[j + 5];
                    a6 += wB[j + 6] * sv[j + 6];
                    a7 += wB[j + 7] * sv[j + 7];
                }
                float acc = c1 + (((a0 + a1) + (a2 + a3)) + ((a4 + a5) + (a6 + a7)));
                float e  = __expf(-2.f * acc);
                float tg = 2.f * __builtin_amdgcn_rcpf(1.f + e) - 1.f;
                hf = hB + 0.25f * (tg - hB);
            }

            // ---- L2: pA = sum_j wA[j] * hf_new[j] ----
            {
                float sv[FD];
#pragma unroll
                for (int j = 0; j < FD; ++j) sv[j] = rl(hf, j);
                float a0 = 0.f, a1 = 0.f, a2 = 0.f, a3 = 0.f;
                float a4 = 0.f, a5 = 0.f, a6 = 0.f, a7 = 0.f;
#pragma unroll
                for (int j = 0; j < FD; j += 8) {
                    a0 += wA[j]     * sv[j];
                    a1 += wA[j + 1] * sv[j + 1];
                    a2 += wA[j + 2] * sv[j + 2];
                    a3 += wA[j + 3] * sv[j + 3];
                    a4 += wA[j + 4] * sv[j + 4];
                    a5 += wA[j + 5] * sv[j + 5];
                    a6 += wA[j + 6] * sv[j + 6];
                    a7 += wA[j + 7] * sv[j + 7];
                }
                pA = (((a0 + a1) + (a2 + a3)) + ((a4 + a5) + (a6 + a7)));
            }

            // ---- slow update: lanes 32-47 sigmoid (sg), lanes 48-63 tanh (st) ----
            {
                float u = bA + pC + pA;
                bool isST = (lane >= 48);
                float e = __expf(isST ? (-2.f * u) : (-u));
                float r = __builtin_amdgcn_rcpf(1.f + e);
                float v = isST ? (2.f * r - 1.f) : r;    // st = (1-e)/(1+e) ; sg = 1/(1+e)
                float stv = __shfl(v, lane + 16, 64);    // lanes 32-47 <- st from lane+16
                float hsn = hs + 0.02f * v * (stv - hs);
                if (lane >= FD && lane < FD + SD) hs = hsn;
            }

            // store concat state
            if (lane < CD) sp[0] = (lane < FD) ? hf : hs;
            sp += CD;
        }
    }
}

// ---------------- K3: vocab logits + per-chunk sumexp (max-free) ----------------
// |logit| <= 48 * 0.0055 * ~1.2 < 0.5 (xavier gain 0.5, bounded state), so
// plain exp-sum is safe in fp32 -> no online max, 1 exp per row.
// Each thread handles 2 timesteps (t, t+256) as float2 -> packed fp32 FMA.
__global__ __launch_bounds__(256) void logits_kernel(
    const float* __restrict__ Wout, const float* __restrict__ bout,
    const float* __restrict__ states, float* __restrict__ pm)
{
    int tb = blockIdx.y * 512 + threadIdx.x;     // t0 = tb, t1 = tb + 256
    int chunk = blockIdx.x;
    int r0 = chunk * ROWS_PER;
    int r1 = min(r0 + ROWS_PER, VOCAB);

    float2 s[CD];
#pragma unroll
    for (int k = 0; k < CD; ++k) {
        s[k].x = states[(size_t)tb * CD + k];
        s[k].y = states[(size_t)(tb + 256) * CD + k];
    }

    float sx = 0.f, sy = 0.f;
    for (int r = r0; r < r1; ++r) {
        const float* w = Wout + (size_t)r * CD;
        float b = bout[r];
        float ax = b, ay = b;
#pragma unroll
        for (int k = 0; k < CD; ++k) {
            float wk = w[k];
            ax += wk * s[k].x;
            ay += wk * s[k].y;
        }
        sx += __expf(ax);
        sy += __expf(ay);
    }
    pm[(size_t)tb * VC + chunk]         = sx;
    pm[(size_t)(tb + 256) * VC + chunk] = sy;
}

// ---------------- K4: target logits ----------------
__global__ __launch_bounds__(256) void tlogit_kernel(
    const int* __restrict__ tok, const float* __restrict__ Wout,
    const float* __restrict__ bout, const float* __restrict__ states,
    float* __restrict__ tl)
{
    int t = blockIdx.x * 256 + threadIdx.x;
    if (t >= NSTEP) return;
    int tgt = tok[t + 1];
    const float* w = Wout + (size_t)tgt * CD;
    float acc = bout[tgt];
#pragma unroll
    for (int k = 0; k < CD; ++k) acc += w[k] * states[(size_t)t * CD + k];
    tl[t] = acc;
}

// ---------------- K5a: per-timestep NLL ----------------
__global__ __launch_bounds__(256) void nll_kernel(
    const float* __restrict__ pm, const float* __restrict__ tl,
    float* __restrict__ nll)
{
    int t = blockIdx.x * 256 + threadIdx.x;
    const float* p = pm + (size_t)t * VC;
    float ssum = 0.f;
#pragma unroll
    for (int c = 0; c < VC; ++c) ssum += p[c];
    nll[t] = __logf(ssum) - tl[t];
}

// ---------------- K5b: mean reduce ----------------
__global__ __launch_bounds__(256) void reduce_kernel(
    const float* __restrict__ nll, float* __restrict__ out)
{
    __shared__ float red[256];
    float local = 0.f;
    for (int t = threadIdx.x; t < NSTEP; t += 256) local += nll[t];
    red[threadIdx.x] = local;
    __syncthreads();
    for (int off = 128; off > 0; off >>= 1) {
        if (threadIdx.x < off) red[threadIdx.x] += red[threadIdx.x + off];
        __syncthreads();
    }
    if (threadIdx.x == 0) out[0] = red[0] / (float)NSTEP;
}

extern "C" void kernel_launch(void* const* d_in, const int* in_sizes, int n_in,
                              void* d_out, int out_size, void* d_ws, size_t ws_size,
                              hipStream_t stream) {
    const int*   tok   = (const int*)  d_in[0];
    const float* embed = (const float*)d_in[1];
    const float* Wgh   = (const float*)d_in[2];
    const float* bgh   = (const float*)d_in[3];
    const float* Wgx   = (const float*)d_in[4];
    const float* Wxp   = (const float*)d_in[5];
    const float* Wff   = (const float*)d_in[6];
    const float* bff   = (const float*)d_in[7];
    const float* Wfs   = (const float*)d_in[8];
    const float* Wxf   = (const float*)d_in[9];
    const float* Wsgf  = (const float*)d_in[10];
    const float* bsgf  = (const float*)d_in[11];
    const float* Wsgs  = (const float*)d_in[12];
    const float* Wss   = (const float*)d_in[13];
    const float* bss   = (const float*)d_in[14];
    const float* Wsf   = (const float*)d_in[15];
    const float* Wout  = (const float*)d_in[16];
    const float* bout  = (const float*)d_in[17];

    float* ws     = (float*)d_ws;
    float* xt     = ws + WS_XT;
    float* states = ws + WS_STATES;
    float* pm     = ws + WS_PM;
    float* tl     = ws + WS_TL;
    float* nll    = ws + WS_NLL;
    float* outf   = (float*)d_out;

    xterm_kernel<<<dim3(NSTEP / 8), dim3(256), 0, stream>>>(tok, embed, Wgx, Wxp, Wxf, xt);
    scan_kernel<<<dim3(1), dim3(64), 0, stream>>>(Wgh, bgh, Wff, bff, Wfs, Wsgf, bsgf,
                                                  Wsgs, Wss, bss, Wsf, xt, states);
    logits_kernel<<<dim3(VC, NSTEP / 512), dim3(256), 0, stream>>>(Wout, bout, states, pm);
    tlogit_kernel<<<dim3(NSTEP / 256), dim3(256), 0, stream>>>(tok, Wout, bout, states, tl);
    nll_kernel<<<dim3(NSTEP / 256), dim3(256), 0, stream>>>(pm, tl, nll);
    reduce_kernel<<<dim3(1), dim3(256), 0, stream>>>(nll, outf);
}

// Round 5
// 3153.192 us; speedup vs baseline: 3.2760x; 1.0163x over previous
//
#include <hip/hip_runtime.h>
#include <hip/hip_bf16.h>
#include <cmath>

#define FD 32
#define SD 16
#define NSTEP 4096
#define VOCAB 50257
#define CD 48            // FD + SD (logical)
#define SROW 64          // states row stride (padded, branchless store)
#define VC 64            // vocab chunks for logits pass
#define ROWS_PER ((VOCAB + VC - 1) / VC)   // 786
#define XSLACK 4         // xt slack rows for prefetch

typedef float v2f __attribute__((ext_vector_type(2)));

// ---------------- workspace layout (floats) ----------------
#define WS_XT     0
#define WS_STATES ((NSTEP + XSLACK) * 96)
#define WS_PM     (WS_STATES + NSTEP * SROW)
#define WS_TL     (WS_PM + NSTEP * VC)
#define WS_NLL    (WS_TL + NSTEP)

// ---------------- K1: precompute token-dependent terms ----------------
__global__ __launch_bounds__(256) void xterm_kernel(
    const int* __restrict__ tok, const float* __restrict__ embed,
    const float* __restrict__ Wgx, const float* __restrict__ Wxp,
    const float* __restrict__ Wxf, float* __restrict__ xt)
{
    int t = blockIdx.x * 8 + (threadIdx.x >> 5);
    int i = threadIdx.x & 31;
    if (t >= NSTEP) return;
    const float* x = embed + (size_t)tok[t] * FD;
    float a0 = 0.f, a1 = 0.f, a2 = 0.f;
#pragma unroll
    for (int j = 0; j < FD; ++j) {
        float xj = x[j];
        a0 += Wgx[i * FD + j] * xj;
        a1 += Wxp[i * FD + j] * xj;
        a2 += Wxf[i * FD + j] * xj;
    }
    xt[t * 96 + i]      = a0;
    xt[t * 96 + 32 + i] = a1;
    xt[t * 96 + 64 + i] = a2;
}

// ---------------- K2: serial scan — LDS broadcast + packed fp32 FMA ----------------
// Lane layout:
//   lanes  0-31 (i): rows of W_gate_h (wA2), W_ff (wB2), W_fs (wC2); state hf[i]
//   lanes 32-47 (s): rows of W_sg_f (wA2), W_sg_s (wC2); state hs[s]
//   lanes 48-63 (s): rows of W_sf   (wA2), W_ss   (wC2)
// Broadcast: producer lanes write state to a 64-slot LDS buffer (branchless,
// 2-way bank aliasing = free); all lanes read back the needed 32/16 floats as
// b128 same-address broadcasts -> values land pair-aligned in VGPRs for
// v_pk_fma_f32. Single wave: no barriers; same-wave LDS ops are in-order.
__global__ __launch_bounds__(64) void scan_kernel(
    const float* __restrict__ Wgh, const float* __restrict__ bgh,
    const float* __restrict__ Wff, const float* __restrict__ bff,
    const float* __restrict__ Wfs,
    const float* __restrict__ Wsgf, const float* __restrict__ bsgf,
    const float* __restrict__ Wsgs, const float* __restrict__ Wss,
    const float* __restrict__ bss, const float* __restrict__ Wsf,
    const float* __restrict__ xt, float* __restrict__ states)
{
    __shared__ float bufS[64];   // hs broadcast (slots 32-47 valid)
    __shared__ float bufA[64];   // hA broadcast (slots 0-31)
    __shared__ float bufB[64];   // hB broadcast (slots 0-31)
    __shared__ float bufF[64];   // hf broadcast (slots 0-31)

    const int lane = threadIdx.x;
    v2f wA2[16], wB2[16], wC2[8];
    float bA = 0.f, bB = 0.f;

    if (lane < FD) {
        const v2f* a = (const v2f*)(Wgh + lane * FD);
        const v2f* b = (const v2f*)(Wff + lane * FD);
#pragma unroll
        for (int j = 0; j < 16; ++j) { wA2[j] = a[j]; wB2[j] = b[j]; }
        const v2f* c = (const v2f*)(Wfs + lane * SD);
#pragma unroll
        for (int k = 0; k < 8; ++k) wC2[k] = c[k];
        bA = bgh[lane]; bB = bff[lane];
    } else if (lane < FD + SD) {
        int s = lane - FD;
        const v2f* a = (const v2f*)(Wsgf + s * FD);
#pragma unroll
        for (int j = 0; j < 16; ++j) { wA2[j] = a[j]; wB2[j] = (v2f){0.f, 0.f}; }
        const v2f* c = (const v2f*)(Wsgs + s * SD);
#pragma unroll
        for (int k = 0; k < 8; ++k) wC2[k] = c[k];
        bA = bsgf[s];
    } else {
        int s = lane - 48;
        const v2f* a = (const v2f*)(Wsf + s * FD);
#pragma unroll
        for (int j = 0; j < 16; ++j) { wA2[j] = a[j]; wB2[j] = (v2f){0.f, 0.f}; }
        const v2f* c = (const v2f*)(Wss + s * SD);
#pragma unroll
        for (int k = 0; k < 8; ++k) wC2[k] = c[k];
        bA = bss[s];
    }

    float hf = 0.f, hs = 0.f, pA = 0.f;
    bufS[lane] = 0.f;                       // initial hs broadcast (zeros)

    const float* xp = xt + (lane & 31);
    float gx = xp[0], px = xp[FD], fx = xp[64];
    float* sp = states + lane;

    const bool isSlowState = (lane >= FD) && (lane < FD + SD);  // hoisted masks
    const bool isFast = (lane < FD);
    const bool isST = (lane >= 48);
    const float tsc = isST ? -2.f : -1.f;

    for (int t = 0; t < NSTEP; ++t) {
        // prefetch next xt row (slack rows cover the tail)
        const float* xq = xp + 96;
        float ngx = xq[0], npx = xq[FD], nfx = xq[64];

        // (1) issue hs broadcast reads early (written end of previous step)
        v2f svs[8];
        {
            const v2f* ps = (const v2f*)bufS;
#pragma unroll
            for (int k = 0; k < 8; ++k) svs[k] = ps[16 + k];   // slots 32-47
        }

        // (2) gate (fast lanes): pA = W_gate_h@hf carried from previous L2
        float ga   = pA + bA + gx;
        float ge   = __expf(-ga);
        float gate = __builtin_amdgcn_rcpf(1.f + ge);
        float hA   = hf + gate * px;

        // (3) broadcast hA
        bufA[lane] = hA;

        // (4) L1: pC = sum_k wC[k]*hs[k]
        float pC;
        {
            v2f c0 = {0.f,0.f}, c1v = {0.f,0.f}, c2 = {0.f,0.f}, c3 = {0.f,0.f};
            c0 += wC2[0] * svs[0]; c1v += wC2[1] * svs[1];
            c2 += wC2[2] * svs[2]; c3  += wC2[3] * svs[3];
            c0 += wC2[4] * svs[4]; c1v += wC2[5] * svs[5];
            c2 += wC2[6] * svs[6]; c3  += wC2[7] * svs[7];
            v2f cs = (c0 + c1v) + (c2 + c3);
            pC = cs.x + cs.y;
        }

        float c1 = bB + fx + pC;   // fast lanes: b_ff + x_drive + W_fs@hs

        // (5) relax 1: broadcast-read hA, matvec with W_ff
        float hB;
        {
            v2f sv[16];
            const v2f* pa = (const v2f*)bufA;
#pragma unroll
            for (int j = 0; j < 16; ++j) sv[j] = pa[j];
            v2f a0={0.f,0.f}, a1={0.f,0.f}, a2={0.f,0.f}, a3={0.f,0.f};
            v2f a4={0.f,0.f}, a5={0.f,0.f}, a6={0.f,0.f}, a7={0.f,0.f};
#pragma unroll
            for (int j = 0; j < 16; j += 8) {
                a0 += wB2[j]     * sv[j];
                a1 += wB2[j + 1] * sv[j + 1];
                a2 += wB2[j + 2] * sv[j + 2];
                a3 += wB2[j + 3] * sv[j + 3];
                a4 += wB2[j + 4] * sv[j + 4];
                a5 += wB2[j + 5] * sv[j + 5];
                a6 += wB2[j + 6] * sv[j + 6];
                a7 += wB2[j + 7] * sv[j + 7];
            }
            v2f r2 = ((a0 + a1) + (a2 + a3)) + ((a4 + a5) + (a6 + a7));
            float acc = c1 + r2.x + r2.y;
            float e  = __expf(-2.f * acc);
            float tg = 2.f * __builtin_amdgcn_rcpf(1.f + e) - 1.f;
            hB = hA + 0.25f * (tg - hA);
        }
        bufB[lane] = hB;

        // (6) relax 2: broadcast-read hB
        {
            v2f sv[16];
            const v2f* pb = (const v2f*)bufB;
#pragma unroll
            for (int j = 0; j < 16; ++j) sv[j] = pb[j];
            v2f a0={0.f,0.f}, a1={0.f,0.f}, a2={0.f,0.f}, a3={0.f,0.f};
            v2f a4={0.f,0.f}, a5={0.f,0.f}, a6={0.f,0.f}, a7={0.f,0.f};
#pragma unroll
            for (int j = 0; j < 16; j += 8) {
                a0 += wB2[j]     * sv[j];
                a1 += wB2[j + 1] * sv[j + 1];
                a2 += wB2[j + 2] * sv[j + 2];
                a3 += wB2[j + 3] * sv[j + 3];
                a4 += wB2[j + 4] * sv[j + 4];
                a5 += wB2[j + 5] * sv[j + 5];
                a6 += wB2[j + 6] * sv[j + 6];
                a7 += wB2[j + 7] * sv[j + 7];
            }
            v2f r2 = ((a0 + a1) + (a2 + a3)) + ((a4 + a5) + (a6 + a7));
            float acc = c1 + r2.x + r2.y;
            float e  = __expf(-2.f * acc);
            float tg = 2.f * __builtin_amdgcn_rcpf(1.f + e) - 1.f;
            hf = hB + 0.25f * (tg - hB);
        }
        bufF[lane] = hf;

        // (7) L2: pA = sum_j wA[j]*hf_new[j]
        {
            v2f sv[16];
            const v2f* pf = (const v2f*)bufF;
#pragma unroll
            for (int j = 0; j < 16; ++j) sv[j] = pf[j];
            v2f a0={0.f,0.f}, a1={0.f,0.f}, a2={0.f,0.f}, a3={0.f,0.f};
            v2f a4={0.f,0.f}, a5={0.f,0.f}, a6={0.f,0.f}, a7={0.f,0.f};
#pragma unroll
            for (int j = 0; j < 16; j += 8) {
                a0 += wA2[j]     * sv[j];
                a1 += wA2[j + 1] * sv[j + 1];
                a2 += wA2[j + 2] * sv[j + 2];
                a3 += wA2[j + 3] * sv[j + 3];
                a4 += wA2[j + 4] * sv[j + 4];
                a5 += wA2[j + 5] * sv[j + 5];
                a6 += wA2[j + 6] * sv[j + 6];
                a7 += wA2[j + 7] * sv[j + 7];
            }
            v2f r2 = ((a0 + a1) + (a2 + a3)) + ((a4 + a5) + (a6 + a7));
            pA = r2.x + r2.y;
        }

        // (8) slow update: lanes 32-47 sigmoid, lanes 48-63 tanh
        {
            float u = bA + pC + pA;
            float e = __expf(tsc * u);
            float r = __builtin_amdgcn_rcpf(1.f + e);
            float v = isST ? (2.f * r - 1.f) : r;
            float stv = __shfl(v, lane + 16, 64);
            float hsn = hs + 0.02f * v * (stv - hs);
            hs = isSlowState ? hsn : hs;
        }
        bufS[lane] = hs;   // rebroadcast for next step's L1

        // (9) branchless state store (stride-64 rows; slots 48-63 unused)
        sp[0] = isFast ? hf : hs;
        sp += SROW;
        xp += 96;
        gx = ngx; px = npx; fx = nfx;
    }
}

// ---------------- K3: vocab logits + per-chunk sumexp (max-free) ----------------
// |logit| < 0.5 (xavier gain 0.5, bounded state) -> plain exp-sum is safe.
// K-packed float2 dot products; 2 timesteps per thread amortize row loads.
__global__ __launch_bounds__(256) void logits_kernel(
    const float* __restrict__ Wout, const float* __restrict__ bout,
    const float* __restrict__ states, float* __restrict__ pm)
{
    int tb = blockIdx.y * 512 + threadIdx.x;     // t0 = tb, t1 = tb + 256
    int chunk = blockIdx.x;
    int r0 = chunk * ROWS_PER;
    int r1 = min(r0 + ROWS_PER, VOCAB);

    v2f s0[24], s1[24];
    {
        const v2f* q0 = (const v2f*)(states + (size_t)tb * SROW);
        const v2f* q1 = (const v2f*)(states + (size_t)(tb + 256) * SROW);
#pragma unroll
        for (int k = 0; k < 24; ++k) { s0[k] = q0[k]; s1[k] = q1[k]; }
    }

    float sx = 0.f, sy = 0.f;
    for (int r = r0; r < r1; ++r) {
        const v2f* w = (const v2f*)(Wout + (size_t)r * CD);
        v2f a0 = {0.f,0.f}, b0 = {0.f,0.f}, a1 = {0.f,0.f}, b1 = {0.f,0.f};
#pragma unroll
        for (int k = 0; k < 24; k += 2) {
            v2f wk0 = w[k], wk1 = w[k + 1];
            a0 += wk0 * s0[k];
            a1 += wk0 * s1[k];
            b0 += wk1 * s0[k + 1];
            b1 += wk1 * s1[k + 1];
        }
        v2f v0 = a0 + b0, v1 = a1 + b1;
        float bo = bout[r];
        sx += __expf(v0.x + v0.y + bo);
        sy += __expf(v1.x + v1.y + bo);
    }
    pm[(size_t)tb * VC + chunk]         = sx;
    pm[(size_t)(tb + 256) * VC + chunk] = sy;
}

// ---------------- K4: target logits ----------------
__global__ __launch_bounds__(256) void tlogit_kernel(
    const int* __restrict__ tok, const float* __restrict__ Wout,
    const float* __restrict__ bout, const float* __restrict__ states,
    float* __restrict__ tl)
{
    int t = blockIdx.x * 256 + threadIdx.x;
    if (t >= NSTEP) return;
    int tgt = tok[t + 1];
    const float* w = Wout + (size_t)tgt * CD;
    float acc = bout[tgt];
#pragma unroll
    for (int k = 0; k < CD; ++k) acc += w[k] * states[(size_t)t * SROW + k];
    tl[t] = acc;
}

// ---------------- K5a: per-timestep NLL ----------------
__global__ __launch_bounds__(256) void nll_kernel(
    const float* __restrict__ pm, const float* __restrict__ tl,
    float* __restrict__ nll)
{
    int t = blockIdx.x * 256 + threadIdx.x;
    const float* p = pm + (size_t)t * VC;
    float ssum = 0.f;
#pragma unroll
    for (int c = 0; c < VC; ++c) ssum += p[c];
    nll[t] = __logf(ssum) - tl[t];
}

// ---------------- K5b: mean reduce ----------------
__global__ __launch_bounds__(256) void reduce_kernel(
    const float* __restrict__ nll, float* __restrict__ out)
{
    __shared__ float red[256];
    float local = 0.f;
    for (int t = threadIdx.x; t < NSTEP; t += 256) local += nll[t];
    red[threadIdx.x] = local;
    __syncthreads();
    for (int off = 128; off > 0; off >>= 1) {
        if (threadIdx.x < off) red[threadIdx.x] += red[threadIdx.x + off];
        __syncthreads();
    }
    if (threadIdx.x == 0) out[0] = red[0] / (float)NSTEP;
}

extern "C" void kernel_launch(void* const* d_in, const int* in_sizes, int n_in,
                              void* d_out, int out_size, void* d_ws, size_t ws_size,
                              hipStream_t stream) {
    const int*   tok   = (const int*)  d_in[0];
    const float* embed = (const float*)d_in[1];
    const float* Wgh   = (const float*)d_in[2];
    const float* bgh   = (const float*)d_in[3];
    const float* Wgx   = (const float*)d_in[4];
    const float* Wxp   = (const float*)d_in[5];
    const float* Wff   = (const float*)d_in[6];
    const float* bff   = (const float*)d_in[7];
    const float* Wfs   = (const float*)d_in[8];
    const float* Wxf   = (const float*)d_in[9];
    const float* Wsgf  = (const float*)d_in[10];
    const float* bsgf  = (const float*)d_in[11];
    const float* Wsgs  = (const float*)d_in[12];
    const float* Wss   = (const float*)d_in[13];
    const float* bss   = (const float*)d_in[14];
    const float* Wsf   = (const float*)d_in[15];
    const float* Wout  = (const float*)d_in[16];
    const float* bout  = (const float*)d_in[17];

    float* ws     = (float*)d_ws;
    float* xt     = ws + WS_XT;
    float* states = ws + WS_STATES;
    float* pm     = ws + WS_PM;
    float* tl     = ws + WS_TL;
    float* nll    = ws + WS_NLL;
    float* outf   = (float*)d_out;

    xterm_kernel<<<dim3(NSTEP / 8), dim3(256), 0, stream>>>(tok, embed, Wgx, Wxp, Wxf, xt);
    scan_kernel<<<dim3(1), dim3(64), 0, stream>>>(Wgh, bgh, Wff, bff, Wfs, Wsgf, bsgf,
                                                  Wsgs, Wss, bss, Wsf, xt, states);
    logits_kernel<<<dim3(VC, NSTEP / 512), dim3(256), 0, stream>>>(Wout, bout, states, pm);
    tlogit_kernel<<<dim3(NSTEP / 256), dim3(256), 0, stream>>>(tok, Wout, bout, states, tl);
    nll_kernel<<<dim3(NSTEP / 256), dim3(256), 0, stream>>>(pm, tl, nll);
    reduce_kernel<<<dim3(1), dim3(256), 0, stream>>>(nll, outf);
}